// Round 2
// baseline (416.806 us; speedup 1.0000x reference)
//
#include <hip/hip_runtime.h>
#include <math.h>

#define TPC 225
#define NCLS 224
#define NHID 1024
#define BATCH 2048
#define CAP 256      // bucket capacity per class (mean ~9.1)
#define LSTRIDE 256  // logits ws row stride (floats)

// ---------------------------------------------------------------------------
// Kernel 1: bucket examples by class. Single block, LDS atomics.
// ---------------------------------------------------------------------------
__global__ __launch_bounds__(256) void hs_bucket(const int* __restrict__ labels,
                                                 int* __restrict__ bucket,
                                                 int* __restrict__ cnt) {
    __shared__ int scnt[NCLS];
    const int t = threadIdx.x;
    for (int i = t; i < NCLS; i += 256) scnt[i] = 0;
    __syncthreads();
    for (int b = t; b < BATCH; b += 256) {
        int lab = labels[b];
        int c = lab / TPC;
        int pos = atomicAdd(&scnt[c], 1);
        bucket[c * CAP + pos] = b;
    }
    __syncthreads();
    for (int i = t; i < NCLS; i += 256) cnt[i] = scnt[i];
}

// ---------------------------------------------------------------------------
// Kernel 2: top logits. 256 blocks x 1024 threads. Block owns 8 rows.
// (unchanged this round — isolate the blogits change for attribution)
// ---------------------------------------------------------------------------
__global__ __launch_bounds__(1024, 4) void hs_tlogits(const float* __restrict__ x,
                                                      const float* __restrict__ W,
                                                      float* __restrict__ tws) {
    __shared__ float red[8 * 8 * 256];  // [wd][row][k] 64 KB
    const int t = threadIdx.x;
    const int lane = t & 63;
    const int wave = t >> 6;
    const int wr = wave & 1;   // row-group 0..1
    const int wd = wave >> 1;  // d-eighth 0..7
    const int r0 = blockIdx.x * 8;

    const float* pj[4];
#pragma unroll
    for (int j = 0; j < 4; j++) {
        int k = 64 * j + lane;
        pj[j] = W + (size_t)wd * 128 * NCLS + (k < NCLS ? k : NCLS - 1);
    }
    const float* xp[4];
#pragma unroll
    for (int rl = 0; rl < 4; rl++)
        xp[rl] = x + (size_t)(r0 + wr * 4 + rl) * NHID + wd * 128;

    float acc[4][4] = {};
    for (int dq = 0; dq < 32; ++dq) {
        float w[4][4];
#pragma unroll
        for (int di = 0; di < 4; di++)
#pragma unroll
            for (int j = 0; j < 4; j++) w[di][j] = pj[j][di * NCLS];
#pragma unroll
        for (int rl = 0; rl < 4; rl++) {
            float4 xq = *(const float4*)(xp[rl] + dq * 4);
#pragma unroll
            for (int di = 0; di < 4; di++) {
                float xv = ((const float*)&xq)[di];
#pragma unroll
                for (int j = 0; j < 4; j++)
                    acc[rl][j] = fmaf(xv, w[di][j], acc[rl][j]);
            }
        }
#pragma unroll
        for (int j = 0; j < 4; j++) pj[j] += 4 * NCLS;
    }
#pragma unroll
    for (int rl = 0; rl < 4; rl++)
#pragma unroll
        for (int j = 0; j < 4; j++)
            red[(wd * 8 + wr * 4 + rl) * 256 + 64 * j + lane] = acc[rl][j];
    __syncthreads();

    const int u = t & 255;
    for (int r = t >> 8; r < 8; r += 4) {
        if (u < NCLS) {
            float s = 0.f;
#pragma unroll
            for (int w8 = 0; w8 < 8; w8++) s += red[(w8 * 8 + r) * 256 + u];
            tws[(size_t)(r0 + r) * LSTRIDE + u] = s;
        }
    }
}

// ---------------------------------------------------------------------------
// Kernel 3 (REWRITTEN): bottom logits, barrier-free d-split.
// Grid = NCLS*4 blocks (one per class x d-quarter), 256 threads = 4 waves =
// 4 row-groups. Each wave accumulates a COMPLETE 256-d quarter partial for
// its rows -> no LDS, no __syncthreads. Weight + x loads double-buffered in
// registers (16 w-loads in flight during each FMA block). Partials written
// to 4 disjoint buffers; hs_finish sums them (deterministic, no atomics).
// ---------------------------------------------------------------------------
#define LOADW(W)                                              \
    do {                                                      \
        _Pragma("unroll") for (int di = 0; di < 4; di++)      \
            _Pragma("unroll") for (int j = 0; j < 4; j++)     \
                W[di][j] = pj[j][di * TPC];                   \
        _Pragma("unroll") for (int j = 0; j < 4; j++)         \
            pj[j] += 4 * TPC;                                 \
    } while (0)

#define LOADX(X, dq)                                          \
    do {                                                      \
        _Pragma("unroll") for (int rl = 0; rl < RW; rl++)     \
            X[rl] = *(const float4*)(xp[rl] + (dq) * 4);      \
    } while (0)

#define FMAS(W, X)                                            \
    do {                                                      \
        _Pragma("unroll") for (int rl = 0; rl < RW; rl++) {   \
            _Pragma("unroll") for (int di = 0; di < 4; di++) {\
                float xv = ((const float*)&X[rl])[di];        \
                _Pragma("unroll") for (int j = 0; j < 4; j++) \
                    acc[rl][j] = fmaf(xv, W[di][j], acc[rl][j]); \
            }                                                 \
        }                                                     \
    } while (0)

template <int RW>
__device__ __forceinline__ void bpass4(const float* __restrict__ xq,
                                       const float* __restrict__ wq,
                                       const int* __restrict__ bucket_c,
                                       const int base, const int n,
                                       const int lane, const int wr,
                                       float* __restrict__ bp) {
    const float* xp[RW];
    int rows[RW];
#pragma unroll
    for (int rl = 0; rl < RW; rl++) {
        int idx = base + wr * RW + rl;
        int row = bucket_c[idx < n ? idx : 0];  // pad rows alias entry 0
        rows[rl] = (idx < n) ? row : -1;
        xp[rl] = xq + (size_t)row * NHID;
    }
    const float* pj[4];
#pragma unroll
    for (int j = 0; j < 4; j++) {
        int k = 64 * j + lane;
        pj[j] = wq + (k < TPC ? k : TPC - 1);
    }
    float acc[RW][4] = {};
    float wA[4][4], wB[4][4];
    float4 xA[RW], xB[RW];

    LOADW(wA);
    LOADX(xA, 0);
    for (int dq = 0; dq < 64; dq += 2) {
        LOADW(wB);                    // prefetch dq+1 weights
        LOADX(xB, dq + 1);            // prefetch dq+1 x
        FMAS(wA, xA);                 // compute dq
        if (dq + 2 < 64) {            // guard: don't read past quarter end
            LOADW(wA);                // prefetch dq+2 weights
            LOADX(xA, dq + 2);
        }
        FMAS(wB, xB);                 // compute dq+1
    }

#pragma unroll
    for (int rl = 0; rl < RW; rl++) {
        if (rows[rl] >= 0) {
#pragma unroll
            for (int j = 0; j < 4; j++) {
                int k = 64 * j + lane;
                if (k < TPC) bp[(size_t)rows[rl] * LSTRIDE + k] = acc[rl][j];
            }
        }
    }
}

__global__ __launch_bounds__(256, 4) void hs_blogits(const float* __restrict__ x,
                                                     const float* __restrict__ Wb,
                                                     const int* __restrict__ bucket,
                                                     const int* __restrict__ cnt,
                                                     float* __restrict__ bws) {
    const int c = blockIdx.x >> 2;   // class
    const int q = blockIdx.x & 3;    // d-quarter
    const int n = cnt[c];
    if (n == 0) return;
    const int lane = threadIdx.x & 63;
    const int wr = threadIdx.x >> 6;  // row-group 0..3
    const float* wq = Wb + (size_t)c * (NHID * TPC) + (size_t)q * 256 * TPC;
    const float* xq = x + q * 256;
    const int* bucket_c = bucket + c * CAP;
    float* bp = bws + (size_t)q * BATCH * LSTRIDE;

    for (int base = 0; base < n; base += 16) {
        int m = n - base;
        if (m > 16) m = 16;
        const int RW = (m + 3) >> 2;
        switch (RW) {  // block-uniform
            case 1: bpass4<1>(xq, wq, bucket_c, base, n, lane, wr, bp); break;
            case 2: bpass4<2>(xq, wq, bucket_c, base, n, lane, wr, bp); break;
            case 3: bpass4<3>(xq, wq, bucket_c, base, n, lane, wr, bp); break;
            default: bpass4<4>(xq, wq, bucket_c, base, n, lane, wr, bp); break;
        }
    }
}

// ---------------------------------------------------------------------------
// Kernel 4: finish. One wave per row: softmax over top (224) and bottom (225)
// logits (bias added here). Bottom logits = sum of 4 d-quarter partials.
// ---------------------------------------------------------------------------
__global__ __launch_bounds__(256) void hs_finish(const float* __restrict__ tws,
                                                 const float* __restrict__ bws,
                                                 const int* __restrict__ labels,
                                                 const float* __restrict__ b_top,
                                                 const float* __restrict__ b_bot,
                                                 float* __restrict__ out) {
    const int lane = threadIdx.x & 63;
    const int wave = threadIdx.x >> 6;
    const int row = blockIdx.x * 4 + wave;
    const int label = labels[row];
    const int c = label / TPC;
    const int word = label - c * TPC;

    float p[2];
#pragma unroll
    for (int lvl = 0; lvl < 2; lvl++) {
        const int NS = lvl ? TPC : NCLS;
        const int pick = lvl ? word : c;
        const float* bias = lvl ? (b_bot + c * TPC) : b_top;
        float lg[4];
#pragma unroll
        for (int j = 0; j < 4; j++) {
            int k = lane + 64 * j;
            if (k < NS) {
                float v;
                if (lvl == 0) {
                    v = tws[(size_t)row * LSTRIDE + k];
                } else {
                    v = bws[(size_t)row * LSTRIDE + k]
                      + bws[(size_t)(BATCH + row) * LSTRIDE + k]
                      + bws[(size_t)(2 * BATCH + row) * LSTRIDE + k]
                      + bws[(size_t)(3 * BATCH + row) * LSTRIDE + k];
                }
                lg[j] = v + bias[k];
            } else {
                lg[j] = -INFINITY;
            }
        }
        float m = fmaxf(fmaxf(lg[0], lg[1]), fmaxf(lg[2], lg[3]));
#pragma unroll
        for (int off = 32; off > 0; off >>= 1) m = fmaxf(m, __shfl_xor(m, off, 64));
        float s = 0.f, pp = 0.f;
#pragma unroll
        for (int j = 0; j < 4; j++) {
            int k = lane + 64 * j;
            float e = (k < NS) ? __expf(lg[j] - m) : 0.f;
            s += e;
            if (k == pick) pp = e;
        }
#pragma unroll
        for (int off = 32; off > 0; off >>= 1) {
            s += __shfl_xor(s, off, 64);
            pp += __shfl_xor(pp, off, 64);
        }
        p[lvl] = pp / s;
    }
    if (lane == 0) out[row] = p[0] * p[1];
}

// ---------------------------------------------------------------------------
extern "C" void kernel_launch(void* const* d_in, const int* in_sizes, int n_in,
                              void* d_out, int out_size, void* d_ws, size_t ws_size,
                              hipStream_t stream) {
    const float* inputs   = (const float*)d_in[0];
    const int*   labels   = (const int*)d_in[1];
    const float* W_top    = (const float*)d_in[2];
    const float* b_top    = (const float*)d_in[3];
    const float* W_bottom = (const float*)d_in[4];
    const float* b_bottom = (const float*)d_in[5];
    float* out = (float*)d_out;

    // ws layout: bucket[NCLS*CAP] | cnt[NCLS] | tws[B*LSTRIDE] | bws[4*B*LSTRIDE]
    int* bucket = (int*)d_ws;
    int* cnt    = bucket + NCLS * CAP;
    float* tws  = (float*)(cnt + NCLS);
    float* bws  = tws + (size_t)BATCH * LSTRIDE;

    hs_bucket<<<1, 256, 0, stream>>>(labels, bucket, cnt);
    hs_tlogits<<<256, 1024, 0, stream>>>(inputs, W_top, tws);
    hs_blogits<<<NCLS * 4, 256, 0, stream>>>(inputs, W_bottom, bucket, cnt, bws);
    hs_finish<<<BATCH / 4, 256, 0, stream>>>(tws, bws, labels, b_top, b_bottom, out);
}